// Round 4
// baseline (592.055 us; speedup 1.0000x reference)
//
#include <hip/hip_runtime.h>
#include <math.h>

#define HW 4096
#define CH 64
#define NCODE 1024
#define FLAGCAP 65536u

// d_out layout (float elements)
#define OUT_IDX  16777216
#define OUT_LOSS 17039360
#define OUT_PERP 17039364

// ws layout (float elements)
#define WS_C2    0        // [4096] f32
#define WS_CNT   4096     // [4096] f32
#define WS_SUM   8192     // [4]    f32
#define WS_FLAGC 8196     // [1]    u32
#define WS_C2D   8200     // [4096] f64 (8192 f32 slots, 8B-aligned)
#define WS_FLAGL 16392    // [65536] u32
#define WS_CBP   81936    // cbpack: 4*1024*128 bf16 = 1 MB, 16B-aligned

typedef short bf16x8 __attribute__((ext_vector_type(8)));
typedef float f32x4v __attribute__((ext_vector_type(4)));

static __device__ __forceinline__ unsigned f2u(float f) { return __float_as_uint(f); }
static __device__ __forceinline__ float u2f(unsigned u) { return __uint_as_float(u); }
static __device__ __forceinline__ unsigned short bf16rne(float f) {
  unsigned u = f2u(f);
  unsigned r = u + 0x7FFFu + ((u >> 16) & 1u);
  return (unsigned short)(r >> 16);
}

// ---------------------------------------------------------------- prep: pack codebooks (-2*cb, RNE hi/lo split,
// frag-linear layout), fp32 c2, fp64 c2, zero accumulators.
__global__ __launch_bounds__(256) void vq_prep(const float* __restrict__ cb0, const float* __restrict__ cb1,
                                               const float* __restrict__ cb2, const float* __restrict__ cb3,
                                               float* __restrict__ ws) {
  int gid = blockIdx.x * 256 + threadIdx.x;  // 0..4095 = layer*1024 + code
  int l = gid >> 10, code = gid & 1023;
  const float* cbs[4] = {cb0, cb1, cb2, cb3};
  const float* row = cbs[l] + (size_t)code * CH;

  unsigned short* cbpack = (unsigned short*)(ws + WS_CBP);
  const int kt = code >> 5, m = (code >> 4) & 1, rowc = code & 15;
  const size_t base = (size_t)l * 131072 + (size_t)kt * 4096;  // ushort offsets

  float c2 = 0.f;
  double c2d = 0.0;
#pragma unroll 8
  for (int c = 0; c < CH; ++c) {
    float v = row[c];
    c2 = fmaf(v, v, c2);
    c2d = fma((double)v, (double)v, c2d);
    float aa = -2.f * v;
    unsigned short ah = bf16rne(aa);
    float rest = aa - u2f((unsigned)ah << 16);
    unsigned short al = bf16rne(rest);
    int s0 = c, s1 = 64 + c;
    cbpack[base + (size_t)(m * 4 + (s0 >> 5)) * 512 + (size_t)(((s0 >> 3) & 3) * 16 + rowc) * 8 + (s0 & 7)] = ah;
    cbpack[base + (size_t)(m * 4 + (s1 >> 5)) * 512 + (size_t)(((s1 >> 3) & 3) * 16 + rowc) * 8 + (s1 & 7)] = al;
  }
  ws[WS_C2 + gid] = c2;
  ((double*)(ws + WS_C2D))[gid] = c2d;
  ws[WS_CNT + gid] = 0.f;
  if (gid < 4) ws[WS_SUM + gid] = 0.f;
  if (gid == 0) *((unsigned*)(ws + WS_FLAGC)) = 0u;
}

// ---------------------------------------------------------------- argmin: MFMA distance GEMM (3-term hi/lo split)
// 1 wave per block; wave owns 64 consecutive pixels; loops all 1024 codes. No LDS.
__global__ __launch_bounds__(64, 4) void vq_argmin(
    const float* __restrict__ x, float* __restrict__ ws, float* __restrict__ out) {
  const int layer = blockIdx.y;
  const int lane = threadIdx.x;
  const int rowl = lane & 15, g = lane >> 4;
  const int g4 = g * 4;

  const int p0 = blockIdx.x * 64;  // pixel base (within layer)
  const int b = p0 >> 12;
  const int hwb = (p0 & 4095) + rowl;
  const float* xb = x + (size_t)(b * 256 + layer * 64) * HW;

  // X frags: xf[n][chunk]; pixel = p0 + n*16 + rowl; chunks: 0=hi ch0-31, 1=hi ch32-63, 2=lo ch0-31, 3=lo ch32-63
  bf16x8 xf[4][4];
  float x2[4];  // full 64-ch ||x||^2 per pixel-slot n
#pragma unroll
  for (int n = 0; n < 4; ++n) {
    int hw = hwb + n * 16;
    float s = 0.f;
#pragma unroll
    for (int j = 0; j < 8; ++j) {
      float v0 = xb[(size_t)(g * 8 + j) * HW + hw];
      float v1 = xb[(size_t)(32 + g * 8 + j) * HW + hw];
      s = fmaf(v0, v0, s);
      s = fmaf(v1, v1, s);
      unsigned short h0 = bf16rne(v0);
      unsigned short h1 = bf16rne(v1);
      float r0 = v0 - u2f((unsigned)h0 << 16);
      float r1 = v1 - u2f((unsigned)h1 << 16);
      xf[n][0][j] = (short)h0;
      xf[n][1][j] = (short)h1;
      xf[n][2][j] = (short)bf16rne(r0);
      xf[n][3][j] = (short)bf16rne(r1);
    }
    s += __shfl_xor(s, 16);
    s += __shfl_xor(s, 32);
    x2[n] = s;
  }

  const unsigned short* cbl = (const unsigned short*)(ws + WS_CBP) + (size_t)layer * 131072;
  const float* c2l = ws + WS_C2 + layer * NCODE;

  float d1[4], d2[4];
#pragma unroll
  for (int n = 0; n < 4; ++n) { d1[n] = 1e30f; d2[n] = 1e30f; }

  const unsigned short* cbase = cbl + lane * 8;

  // per-half compute: 16 codes (hh in [0,64)), frags R0..R3
  auto compute_half = [&](int hh, bf16x8 R0, bf16x8 R1, bf16x8 R2, bf16x8 R3) {
    f32x4v c2v = *(const f32x4v*)(c2l + hh * 16 + g4);
    unsigned kb0 = (unsigned)(hh * 16 + g4);
#pragma unroll
    for (int n = 0; n < 4; ++n) {
      f32x4v a;
      a[0] = c2v[0] + x2[n]; a[1] = c2v[1] + x2[n];
      a[2] = c2v[2] + x2[n]; a[3] = c2v[3] + x2[n];
      a = __builtin_amdgcn_mfma_f32_16x16x32_bf16(R0, xf[n][0], a, 0, 0, 0);  // hi*hi ch0-31
      a = __builtin_amdgcn_mfma_f32_16x16x32_bf16(R1, xf[n][1], a, 0, 0, 0);  // hi*hi ch32-63
      a = __builtin_amdgcn_mfma_f32_16x16x32_bf16(R2, xf[n][0], a, 0, 0, 0);  // c_lo*x_hi
      a = __builtin_amdgcn_mfma_f32_16x16x32_bf16(R3, xf[n][1], a, 0, 0, 0);
      a = __builtin_amdgcn_mfma_f32_16x16x32_bf16(R0, xf[n][2], a, 0, 0, 0);  // c_hi*x_lo
      a = __builtin_amdgcn_mfma_f32_16x16x32_bf16(R1, xf[n][3], a, 0, 0, 0);
#pragma unroll
      for (int r = 0; r < 4; ++r) {
        float pd = u2f((f2u(a[r]) & 0xFFFFFC00u) | (kb0 + r));  // v_and_or_b32
        float t = d1[n];
        d1[n] = fminf(t, pd);
        d2[n] = __builtin_amdgcn_fmed3f(t, d2[n], pd);
      }
    }
  };

  bf16x8 A0, A1, A2, A3, B0, B1, B2, B3;
  A0 = *(const bf16x8*)(cbase + 0);
  A1 = *(const bf16x8*)(cbase + 512);
  A2 = *(const bf16x8*)(cbase + 1024);
  A3 = *(const bf16x8*)(cbase + 1536);
  for (int h = 0; h < 62; h += 2) {
    const unsigned short* p1 = cbase + (size_t)(h + 1) * 2048;
    B0 = *(const bf16x8*)(p1 + 0);
    B1 = *(const bf16x8*)(p1 + 512);
    B2 = *(const bf16x8*)(p1 + 1024);
    B3 = *(const bf16x8*)(p1 + 1536);
    compute_half(h, A0, A1, A2, A3);
    const unsigned short* p2 = cbase + (size_t)(h + 2) * 2048;
    A0 = *(const bf16x8*)(p2 + 0);
    A1 = *(const bf16x8*)(p2 + 512);
    A2 = *(const bf16x8*)(p2 + 1024);
    A3 = *(const bf16x8*)(p2 + 1536);
    compute_half(h + 1, B0, B1, B2, B3);
  }
  {
    const unsigned short* p1 = cbase + (size_t)63 * 2048;
    B0 = *(const bf16x8*)(p1 + 0);
    B1 = *(const bf16x8*)(p1 + 512);
    B2 = *(const bf16x8*)(p1 + 1024);
    B3 = *(const bf16x8*)(p1 + 1536);
    compute_half(62, A0, A1, A2, A3);
    compute_half(63, B0, B1, B2, B3);
  }

  // merge across the 4 lane-groups (xor 16, 32); all lanes converge
  unsigned* flagcnt = (unsigned*)(ws + WS_FLAGC);
  unsigned* flaglist = (unsigned*)(ws + WS_FLAGL);
  float sse = 0.f;
#pragma unroll
  for (int n = 0; n < 4; ++n) {
    float e1 = d1[n], e2 = d2[n];
#pragma unroll
    for (int off = 16; off <= 32; off <<= 1) {
      float o1 = __shfl_xor(e1, off);
      float o2 = __shfl_xor(e2, off);
      float t = fmaxf(e1, o1);
      e1 = fminf(e1, o1);
      e2 = fminf(fminf(t, e2), o2);
    }
    float du1 = u2f(f2u(e1) & 0xFFFFFC00u);  // true squared distance (quantized)
    sse += du1;
    if (g == 0) {
      int p = p0 + n * 16 + rowl;
      int hw = p & 4095;
      size_t orow = (size_t)(b * 4 + layer) * HW + hw;
      out[OUT_IDX + orow] = (float)(f2u(e1) & 1023u);
      float du2 = u2f(f2u(e2) & 0xFFFFFC00u);
      float tau2 = fmaf(du1, 3e-4f, 0.05f);  // adaptive: covers pack quantization
      if (du2 - du1 < tau2) {
        unsigned pos = atomicAdd(flagcnt, 1u);
        if (pos < FLAGCAP) flaglist[pos] = (unsigned)orow;
      }
    }
  }
  // SSE: every lane holds per-pixel du1 copies (x4 groups identical); butterfly within 16-lane quarter
  sse += __shfl_xor(sse, 1);
  sse += __shfl_xor(sse, 2);
  sse += __shfl_xor(sse, 4);
  sse += __shfl_xor(sse, 8);
  if (lane == 0) atomicAdd(&ws[WS_SUM + layer], sse);
}

// ---------------------------------------------------------------- fp64 re-rank of flagged rows (list-driven)
__global__ __launch_bounds__(64) void vq_refine(
    const float* __restrict__ x,
    const float* __restrict__ cb0, const float* __restrict__ cb1,
    const float* __restrict__ cb2, const float* __restrict__ cb3,
    float* __restrict__ ws, float* __restrict__ out) {
  unsigned count = *((const unsigned*)(ws + WS_FLAGC));
  if (count > FLAGCAP) count = FLAGCAP;
  const unsigned* flaglist = (const unsigned*)(ws + WS_FLAGL);
  const int tid = threadIdx.x;

  for (unsigned i = blockIdx.x; i < count; i += gridDim.x) {
    unsigned r = flaglist[i];
    int l = (r >> 12) & 3;
    int bb = r >> 14;
    int hw = r & 4095;
    const float* cb = (l == 0) ? cb0 : (l == 1) ? cb1 : (l == 2) ? cb2 : cb3;
    const double* c2d = (const double*)(ws + WS_C2D) + l * NCODE;
    const float* xb = x + (size_t)(bb * 256 + l * 64) * HW + hw;
    float f[CH];
#pragma unroll
    for (int c = 0; c < CH; ++c) f[c] = xb[(size_t)c * HW];
    int old = (int)out[OUT_IDX + r];

    double bd = 1e300, sOld = 1e300;
    int bk = 0;
    for (int j = 0; j < 16; ++j) {
      int k = (j << 6) | tid;
      const float* cr = cb + (size_t)k * CH;
      double dot = 0.0;
#pragma unroll
      for (int c4 = 0; c4 < 16; ++c4) {
        float4 cv = *(const float4*)(cr + c4 * 4);
        dot = fma((double)cv.x, (double)f[c4 * 4 + 0], dot);
        dot = fma((double)cv.y, (double)f[c4 * 4 + 1], dot);
        dot = fma((double)cv.z, (double)f[c4 * 4 + 2], dot);
        dot = fma((double)cv.w, (double)f[c4 * 4 + 3], dot);
      }
      double sc = fma(-2.0, dot, c2d[k]);  // score (x^2 omitted, cancels)
      if (sc < bd || (sc == bd && k < bk)) { bd = sc; bk = k; }
      if (k == old) sOld = sc;
    }
    for (int off = 1; off < 64; off <<= 1) {
      double od = __shfl_xor(bd, off);
      int ok = __shfl_xor(bk, off);
      double os = __shfl_xor(sOld, off);
      if (od < bd || (od == bd && ok < bk)) { bd = od; bk = ok; }
      sOld = fmin(sOld, os);
    }
    if (tid == 0 && bk != old) {
      out[OUT_IDX + r] = (float)bk;
      atomicAdd(&ws[WS_SUM + l], (float)(bd - sOld));  // exact SSE patch
    }
  }
}

// ---------------------------------------------------------------- gather (write-only quant) + LDS histogram
__global__ __launch_bounds__(256) void vq_gather(
    const float* __restrict__ cb0, const float* __restrict__ cb1,
    const float* __restrict__ cb2, const float* __restrict__ cb3,
    float* __restrict__ out, float* __restrict__ ws) {
  __shared__ unsigned hist[NCODE];
  const int layer = blockIdx.y;
  const int t = threadIdx.x;
  const float* cb = (layer == 0) ? cb0 : (layer == 1) ? cb1 : (layer == 2) ? cb2 : cb3;

  for (int i = t; i < NCODE; i += 256) hist[i] = 0u;
  __syncthreads();

  const int p = blockIdx.x * 256 + t;  // pixel within layer
  const int bb = p >> 12, hw = p & 4095;
  const int k = (int)out[OUT_IDX + (size_t)(bb * 4 + layer) * HW + hw];
  atomicAdd(&hist[k], 1u);

  const float* cr = cb + (size_t)k * CH;
  float* qp = out + (size_t)(bb * 256 + layer * 64) * HW + hw;
#pragma unroll
  for (int c4 = 0; c4 < 16; ++c4) {
    float4 cv = *(const float4*)(cr + c4 * 4);
    qp[(size_t)(c4 * 4 + 0) * HW] = cv.x;
    qp[(size_t)(c4 * 4 + 1) * HW] = cv.y;
    qp[(size_t)(c4 * 4 + 2) * HW] = cv.z;
    qp[(size_t)(c4 * 4 + 3) * HW] = cv.w;
  }

  __syncthreads();
  for (int i = t; i < NCODE; i += 256) {
    unsigned h = hist[i];
    if (h) atomicAdd(&ws[WS_CNT + layer * NCODE + i], (float)h);
  }
}

// ---------------------------------------------------------------- loss + perplexity
__global__ __launch_bounds__(256) void vq_final(const float* __restrict__ ws, float* __restrict__ out) {
  const int l = blockIdx.x;
  float h = 0.f;
#pragma unroll
  for (int j = 0; j < 4; ++j) {
    float cnt = ws[WS_CNT + l * NCODE + threadIdx.x + j * 256];
    float pr = cnt * (1.f / 65536.f);
    h += pr * logf(pr + 1e-10f);
  }
  __shared__ float red[256];
  red[threadIdx.x] = h;
  __syncthreads();
  for (int s = 128; s > 0; s >>= 1) {
    if (threadIdx.x < s) red[threadIdx.x] += red[threadIdx.x + s];
    __syncthreads();
  }
  if (threadIdx.x == 0) {
    out[OUT_LOSS + l] = 1.25f * ws[WS_SUM + l] / 4194304.f;
    out[OUT_PERP + l] = expf(-red[0]);
  }
}

// ---------------------------------------------------------------- launch
extern "C" void kernel_launch(void* const* d_in, const int* in_sizes, int n_in,
                              void* d_out, int out_size, void* d_ws, size_t ws_size,
                              hipStream_t stream) {
  const float* x = (const float*)d_in[0];
  const float* cb0 = (const float*)d_in[1];
  const float* cb1 = (const float*)d_in[2];
  const float* cb2 = (const float*)d_in[3];
  const float* cb3 = (const float*)d_in[4];
  float* out = (float*)d_out;
  float* ws = (float*)d_ws;

  vq_prep  <<<dim3(16),      dim3(256), 0, stream>>>(cb0, cb1, cb2, cb3, ws);
  vq_argmin<<<dim3(1024, 4), dim3(64),  0, stream>>>(x, ws, out);
  vq_refine<<<dim3(2048),    dim3(64),  0, stream>>>(x, cb0, cb1, cb2, cb3, ws, out);
  vq_gather<<<dim3(256, 4),  dim3(256), 0, stream>>>(cb0, cb1, cb2, cb3, out, ws);
  vq_final <<<dim3(4),       dim3(256), 0, stream>>>(ws, out);
}